// Round 1
// baseline (3732.144 us; speedup 1.0000x reference)
//
#include <hip/hip_runtime.h>
#include <hip/hip_bf16.h>

#define DIM  128
#define HWSZ 196
#define CCH  256
#define KTOT (CCH*HWSZ)   // 50176

// ---------------- obj_feats: relu([roi|logit|bbox]@We1+be1)@We2+be2 -> h[0:48] ----
__global__ __launch_bounds__(128) void k_objfeats(
    const float* __restrict__ roi, const float* __restrict__ logit,
    const float* __restrict__ bbox,
    const float* __restrict__ We1, const float* __restrict__ be1,
    const float* __restrict__ We2, const float* __restrict__ be2,
    float* __restrict__ h) {
  const int i = blockIdx.x, j = threadIdx.x;
  __shared__ float t1[DIM];
  float acc = be1[j];
  const float* r = roi + (size_t)i*4096;
  for (int k = 0; k < 4096; ++k) acc = fmaf(r[k], We1[(size_t)k*DIM + j], acc);
  const float* lg = logit + (size_t)i*151;
  for (int k = 0; k < 151; ++k) acc = fmaf(lg[k], We1[(size_t)(4096+k)*DIM + j], acc);
  const float* bb = bbox + (size_t)i*4;
  for (int k = 0; k < 4; ++k) acc = fmaf(bb[k], We1[(size_t)(4247+k)*DIM + j], acc);
  t1[j] = fmaxf(acc, 0.f);
  __syncthreads();
  float a2 = be2[j];
  for (int k = 0; k < DIM; ++k) a2 = fmaf(t1[k], We2[k*DIM + j], a2);
  h[(size_t)i*DIM + j] = a2;
}

// ---------------- per-pair box masks -> 2-bit code (s | o<<1) per (m,hw) --------
__global__ void k_masks(const float* __restrict__ bbox, const int* __restrict__ pairs,
                        int M, unsigned char* __restrict__ code) {
  int m = blockIdx.x * blockDim.x + threadIdx.x;
  if (m >= M) return;
  int s = pairs[2*m], o = pairs[2*m+1];
  float sx1=bbox[4*s],   sy1=bbox[4*s+1], sx2=bbox[4*s+2], sy2=bbox[4*s+3];
  float ox1=bbox[4*o],   oy1=bbox[4*o+1], ox2=bbox[4*o+2], oy2=bbox[4*o+3];
  float ux = fminf(sx1, ox1), uy = fminf(sy1, oy1);
  float x0=sx1-ux, x1=sx2-ux, x2=ox1-ux, x3=ox2-ux;
  float y0=sy1-uy, y1=sy2-uy, y2=oy1-uy, y3=oy2-uy;
  float xf = 14.f / fmaxf(x1, x3);
  float yf = 14.f / fmaxf(y1, y3);
  int xp0=(int)rintf(x0*xf), xp1=(int)rintf(x1*xf), xp2=(int)rintf(x2*xf), xp3=(int)rintf(x3*xf);
  int yp0=(int)rintf(y0*yf), yp1=(int)rintf(y1*yf), yp2=(int)rintf(y2*yf), yp3=(int)rintf(y3*yf);
  unsigned char* cm = code + (size_t)m*HWSZ;
  for (int hh = 0; hh < 14; ++hh)
    for (int ww = 0; ww < 14; ++ww) {
      int sm = (hh>=xp0 && hh<xp1 && ww>=yp0 && ww<yp1) ? 1 : 0;
      int om = (hh>=xp2 && hh<xp3 && ww>=yp2 && ww<yp3) ? 1 : 0;
      cm[hh*14+ww] = (unsigned char)(sm | (om<<1));
    }
}

// ---------------- combined weights Cs[t][c*196+hw][j] = sum_d Wc[d,c]*W_t[d*196+hw, j]
// plus cbias[t][hw][j] = sum_d bc[d]*W_t[d*196+hw][j]
__global__ __launch_bounds__(128) void k_build_cs(
    const float* __restrict__ Wc, const float* __restrict__ bc,
    const float* __restrict__ Ws, const float* __restrict__ Wob, const float* __restrict__ Wbgm,
    __hip_bfloat16* __restrict__ Cs, float* __restrict__ cbias) {
  const int hw = blockIdx.x;        // 0..195
  const int c0 = blockIdx.y * 32;   // 8 chunks of 32 channels
  const int t  = blockIdx.z;        // mask id
  const float* __restrict__ W = (t==0) ? Ws : (t==1) ? Wob : Wbgm;
  const int tid = threadIdx.x;
  const int jg = tid & 31;          // j = jg*4 + q
  const int cg = tid >> 5;          // ci = cg*8 + i
  __shared__ float Wcl[128][32];
  __shared__ float Wl[32][128];
  for (int idx = tid; idx < 128*32; idx += 128) {
    int dd = idx >> 5, ci = idx & 31;
    Wcl[dd][ci] = Wc[dd*CCH + c0 + ci];
  }
  float acc[8][4];
  #pragma unroll
  for (int a=0;a<8;++a) { acc[a][0]=0.f; acc[a][1]=0.f; acc[a][2]=0.f; acc[a][3]=0.f; }
  float accb[4] = {0.f,0.f,0.f,0.f};
  for (int d0 = 0; d0 < 128; d0 += 32) {
    __syncthreads();
    for (int idx = tid; idx < 32*128; idx += 128) {
      int dd = idx >> 7, jj = idx & 127;
      Wl[dd][jj] = W[((size_t)(d0+dd)*HWSZ + hw)*DIM + jj];
    }
    __syncthreads();
    for (int dd = 0; dd < 32; ++dd) {
      int d = d0 + dd;
      float a8[8], b4[4];
      *(float4*)&a8[0] = *(const float4*)&Wcl[d][cg*8];
      *(float4*)&a8[4] = *(const float4*)&Wcl[d][cg*8+4];
      *(float4*)&b4[0] = *(const float4*)&Wl[dd][jg*4];
      float bcv = bc[d];
      #pragma unroll
      for (int q=0;q<4;++q) accb[q] = fmaf(bcv, b4[q], accb[q]);
      #pragma unroll
      for (int ci=0;ci<8;++ci)
        #pragma unroll
        for (int q=0;q<4;++q)
          acc[ci][q] = fmaf(a8[ci], b4[q], acc[ci][q]);
    }
  }
  for (int ci=0;ci<8;++ci) {
    int c = c0 + cg*8 + ci;
    __hip_bfloat16* cp = Cs + (size_t)t*KTOT*DIM + ((size_t)c*HWSZ + hw)*DIM + jg*4;
    for (int q=0;q<4;++q) cp[q] = __float2bfloat16(acc[ci][q]);
  }
  if (blockIdx.y == 0 && cg == 0) {
    float* cb = cbias + ((size_t)t*HWSZ + hw)*DIM + jg*4;
    for (int q=0;q<4;++q) cb[q] = accb[q];
  }
}

// ---------------- main fused masked GEMM: partial[kc][m][t][j] over 32-channel K chunk
__global__ __launch_bounds__(256) void k_bigproj(
    const float* __restrict__ uni, const __hip_bfloat16* __restrict__ Cs,
    const unsigned char* __restrict__ code, float* __restrict__ part, int M) {
  const int t  = blockIdx.x;        // mask id (fastest -> L2/LLC reuse of union tile)
  const int mt = blockIdx.y;        // m tile of 64
  const int kc = blockIdx.z;        // split-K chunk (32 channels)
  const int m0 = mt * 64;
  const int tid = threadIdx.x;
  const int ty = tid >> 5;          // 0..7 : m-group (8 m each)
  const int tx = tid & 31;          // 0..31: j-group (4 j each)
  const __hip_bfloat16* __restrict__ Bt = Cs + (size_t)t*KTOT*DIM;

  __shared__ float As[16][68];      // [k][m], padded
  __shared__ float Bs[16][128];     // [k][j]
  __shared__ unsigned char codeL[64][HWSZ];

  for (int idx = tid; idx < 64*HWSZ; idx += 256) {
    int lm = idx / HWSZ, hw = idx - lm*HWSZ;
    int gm = m0 + lm;
    codeL[lm][hw] = (gm < M) ? code[(size_t)gm*HWSZ + hw] : (unsigned char)0;
  }
  __syncthreads();

  float acc[8][4];
  #pragma unroll
  for (int a=0;a<8;++a) { acc[a][0]=0.f; acc[a][1]=0.f; acc[a][2]=0.f; acc[a][3]=0.f; }

  for (int ci = 0; ci < 32; ++ci) {
    const int c = kc*32 + ci;
    for (int hw0 = 0; hw0 < HWSZ; hw0 += 16) {
      const int bk = min(16, HWSZ - hw0);   // 16 or 4
      __syncthreads();
      { // stage A (masked union)
        const int lm = tid >> 2;
        const int lk0 = (tid & 3) * 4;
        const int gm = m0 + lm;
        float v[4] = {0.f,0.f,0.f,0.f};
        if (gm < M && lk0 < bk) {
          const float* up = uni + (size_t)gm*KTOT + (size_t)c*HWSZ + hw0 + lk0;
          float4 u4 = *(const float4*)up;
          v[0]=u4.x; v[1]=u4.y; v[2]=u4.z; v[3]=u4.w;
          #pragma unroll
          for (int q=0;q<4;++q) {
            int cd = codeL[lm][hw0+lk0+q];
            float mv = (t==0) ? (float)(cd&1) : (t==1) ? (float)((cd>>1)&1) : ((cd==0)?1.f:0.f);
            v[q] *= mv;
          }
        }
        #pragma unroll
        for (int q=0;q<4;++q) As[lk0+q][lm] = v[q];
      }
      { // stage B (bf16 combined weights -> f32)
        const int lk = tid >> 4;
        const int lj = (tid & 15) * 8;
        float f[8];
        if (lk < bk) {
          const __hip_bfloat16* bp = Bt + ((size_t)c*HWSZ + hw0 + lk)*DIM + lj;
          const uint4 rv = *(const uint4*)bp;
          f[0]=__uint_as_float(rv.x<<16); f[1]=__uint_as_float(rv.x&0xffff0000u);
          f[2]=__uint_as_float(rv.y<<16); f[3]=__uint_as_float(rv.y&0xffff0000u);
          f[4]=__uint_as_float(rv.z<<16); f[5]=__uint_as_float(rv.z&0xffff0000u);
          f[6]=__uint_as_float(rv.w<<16); f[7]=__uint_as_float(rv.w&0xffff0000u);
        } else {
          #pragma unroll
          for (int q=0;q<8;++q) f[q]=0.f;
        }
        #pragma unroll
        for (int q=0;q<8;++q) Bs[lk][lj+q] = f[q];
      }
      __syncthreads();
      #pragma unroll
      for (int k = 0; k < 16; ++k) {
        float am[8], bj[4];
        *(float4*)&am[0] = *(const float4*)&As[k][ty*8];
        *(float4*)&am[4] = *(const float4*)&As[k][ty*8+4];
        *(float4*)&bj[0] = *(const float4*)&Bs[k][tx*4];
        #pragma unroll
        for (int mi=0;mi<8;++mi)
          #pragma unroll
          for (int ji=0;ji<4;++ji)
            acc[mi][ji] = fmaf(am[mi], bj[ji], acc[mi][ji]);
      }
    }
  }
  #pragma unroll
  for (int mi=0;mi<8;++mi) {
    int gm = m0 + ty*8 + mi;
    if (gm < M) {
      float* pp = part + (((size_t)kc*M + gm)*3 + t)*DIM + tx*4;
      pp[0]=acc[mi][0]; pp[1]=acc[mi][1]; pp[2]=acc[mi][2]; pp[3]=acc[mi][3];
    }
  }
}

// ---------------- reduce partials + bias + mask-weighted cbias -> xseq (M,3,128) ---
__global__ __launch_bounds__(128) void k_reduce_out3(
    const float* __restrict__ part, const unsigned char* __restrict__ code,
    const float* __restrict__ cbias,
    const float* __restrict__ bs, const float* __restrict__ bob, const float* __restrict__ bbgm,
    float* __restrict__ out3, int M) {
  const int m = blockIdx.x, j = threadIdx.x;
  const unsigned char* cm = code + (size_t)m*HWSZ;
  float a0 = bs[j], a1 = bob[j], a2 = bbgm[j];
  for (int hw = 0; hw < HWSZ; ++hw) {
    int cd = cm[hw];
    if (cd & 1)  a0 += cbias[(size_t)(0*HWSZ+hw)*DIM + j];
    if (cd & 2)  a1 += cbias[(size_t)(1*HWSZ+hw)*DIM + j];
    if (cd == 0) a2 += cbias[(size_t)(2*HWSZ+hw)*DIM + j];
  }
  float a[3] = {a0, a1, a2};
  for (int t = 0; t < 3; ++t) {
    float s = a[t];
    for (int kc = 0; kc < 8; ++kc) s += part[(((size_t)kc*M + m)*3 + t)*DIM + j];
    out3[((size_t)m*3 + t)*DIM + j] = s;
  }
}

// ---------------- per-pair 3-token attention + rel MLP -> h[48+m] -----------------
__global__ __launch_bounds__(128) void k_attention(
    const float* __restrict__ xseq,
    const float* __restrict__ Wq, const float* __restrict__ bq,
    const float* __restrict__ Wk, const float* __restrict__ bk_,
    const float* __restrict__ Wv, const float* __restrict__ bv,
    const float* __restrict__ Wo, const float* __restrict__ bo,
    const float* __restrict__ Wr1, const float* __restrict__ br1,
    const float* __restrict__ Wr2, const float* __restrict__ br2,
    float* __restrict__ h, int M, int N) {
  const int m = blockIdx.x, j = threadIdx.x;
  __shared__ float X[3][DIM], Q[3][DIM], Kx[3][DIM], V[3][DIM], O[3][DIM], P[8][3][3], R[DIM];
  #pragma unroll
  for (int t=0;t<3;++t) X[t][j] = xseq[((size_t)m*3+t)*DIM + j];
  __syncthreads();
  {
    float aq[3], ak[3], av[3];
    #pragma unroll
    for (int t=0;t<3;++t) { aq[t]=bq[j]; ak[t]=bk_[j]; av[t]=bv[j]; }
    for (int k=0;k<DIM;++k) {
      float wq=Wq[k*DIM+j], wk=Wk[k*DIM+j], wv=Wv[k*DIM+j];
      #pragma unroll
      for (int t=0;t<3;++t) {
        float x = X[t][k];
        aq[t]=fmaf(x,wq,aq[t]); ak[t]=fmaf(x,wk,ak[t]); av[t]=fmaf(x,wv,av[t]);
      }
    }
    #pragma unroll
    for (int t=0;t<3;++t) { Q[t][j]=aq[t]; Kx[t][j]=ak[t]; V[t][j]=av[t]; }
  }
  __syncthreads();
  if (j < 72) {
    int hh=j/9, rem=j%9, qt=rem/3, kt=rem%3;
    float s=0.f;
    for (int d=0; d<16; ++d) s = fmaf(Q[qt][hh*16+d], Kx[kt][hh*16+d], s);
    P[hh][qt][kt] = s * 0.25f;
  }
  __syncthreads();
  if (j < 24) {
    int hh=j/3, qt=j%3;
    float s0=P[hh][qt][0], s1=P[hh][qt][1], s2=P[hh][qt][2];
    float mx=fmaxf(s0,fmaxf(s1,s2));
    float e0=expf(s0-mx), e1=expf(s1-mx), e2=expf(s2-mx);
    float inv=1.f/(e0+e1+e2);
    P[hh][qt][0]=e0*inv; P[hh][qt][1]=e1*inv; P[hh][qt][2]=e2*inv;
  }
  __syncthreads();
  {
    int hh = j >> 4;
    #pragma unroll
    for (int qt=0;qt<3;++qt)
      O[qt][j] = P[hh][qt][0]*V[0][j] + P[hh][qt][1]*V[1][j] + P[hh][qt][2]*V[2][j];
  }
  __syncthreads();
  {
    float a[3] = {bo[j], bo[j], bo[j]};
    for (int k=0;k<DIM;++k) {
      float w = Wo[k*DIM+j];
      #pragma unroll
      for (int qt=0;qt<3;++qt) a[qt] = fmaf(O[qt][k], w, a[qt]);
    }
    __syncthreads();
    #pragma unroll
    for (int qt=0;qt<3;++qt) X[qt][j] = a[qt];
  }
  __syncthreads();
  {
    float a = br1[j];
    for (int t=0;t<3;++t)
      for (int k=0;k<DIM;++k) a = fmaf(X[t][k], Wr1[(size_t)(t*DIM+k)*DIM + j], a);
    R[j] = fmaxf(a, 0.f);
  }
  __syncthreads();
  {
    float a = br2[j];
    for (int k=0;k<DIM;++k) a = fmaf(R[k], Wr2[k*DIM+j], a);
    h[((size_t)(N+m))*DIM + j] = a;
  }
}

// ---------------- dense adjacency build + normalize ------------------------------
__global__ void k_adj_init(float* __restrict__ adj, int NM) {
  int idx = blockIdx.x*256 + threadIdx.x;
  if (idx < NM*NM) adj[idx] = (idx / NM == idx % NM) ? 1.f : 0.f;
}

__global__ void k_adj_scatter(const int* __restrict__ pairs, float* __restrict__ adj,
                              int M, int N) {
  int e = blockIdx.x*blockDim.x + threadIdx.x;
  if (e >= M) return;
  int s = pairs[2*e], o = pairs[2*e+1];
  int NM = N + M;
  adj[(size_t)s*NM + o] = 1.f;
  adj[(size_t)s*NM + N + e] = 1.f;
  adj[(size_t)o*NM + N + e] = 1.f;
  adj[(size_t)(N+e)*NM + s] = 1.f;
  adj[(size_t)(N+e)*NM + o] = 1.f;
  int klo = min(s,o), khi = max(s,o);
  for (int f = 0; f < M; ++f) {
    if (f == e) continue;
    int fs = pairs[2*f], fo = pairs[2*f+1];
    if (min(fs,fo)==klo && max(fs,fo)==khi) adj[(size_t)(N+e)*NM + (N+f)] = 1.f;
  }
}

__global__ __launch_bounds__(256) void k_adj_norm(float* __restrict__ adj, int NM) {
  int r = blockIdx.x;
  __shared__ float red[256];
  float s = 0.f;
  for (int c = threadIdx.x; c < NM; c += 256) s += adj[(size_t)r*NM + c];
  red[threadIdx.x] = s;
  __syncthreads();
  for (int st = 128; st > 0; st >>= 1) {
    if (threadIdx.x < st) red[threadIdx.x] += red[threadIdx.x + st];
    __syncthreads();
  }
  float inv = 1.f / red[0];
  for (int c = threadIdx.x; c < NM; c += 256) adj[(size_t)r*NM + c] *= inv;
}

// ---------------- GCN: t = h@W ; h' = relu(adjn@t + b) + h ------------------------
__global__ __launch_bounds__(128) void k_gcn_lin(
    const float* __restrict__ h, const float* __restrict__ W,
    float* __restrict__ t, int NM) {
  int r = blockIdx.x, j = threadIdx.x;
  __shared__ float x[DIM];
  x[j] = h[(size_t)r*DIM + j];
  __syncthreads();
  float a = 0.f;
  for (int k = 0; k < DIM; k += 4) {
    float4 xv = *(const float4*)&x[k];
    a = fmaf(xv.x, W[(k  )*DIM+j], a);
    a = fmaf(xv.y, W[(k+1)*DIM+j], a);
    a = fmaf(xv.z, W[(k+2)*DIM+j], a);
    a = fmaf(xv.w, W[(k+3)*DIM+j], a);
  }
  t[(size_t)r*DIM + j] = a;
}

__global__ __launch_bounds__(128) void k_gcn_spmm(
    const float* __restrict__ adjn, const float* __restrict__ tt,
    const float* __restrict__ bias, const float* __restrict__ hin,
    float* __restrict__ hout, int NM) {
  int r0 = blockIdx.x * 16;
  int j = threadIdx.x;
  float acc[16];
  #pragma unroll
  for (int i=0;i<16;++i) acc[i]=0.f;
  __shared__ float at[16][132];
  for (int c0 = 0; c0 < NM; c0 += 128) {
    __syncthreads();
    for (int idx = j; idx < 16*128; idx += 128) {
      int ri = idx >> 7, cc = idx & 127;
      at[ri][cc] = (r0+ri < NM) ? adjn[(size_t)(r0+ri)*NM + c0 + cc] : 0.f;
    }
    __syncthreads();
    for (int cc = 0; cc < 128; cc += 4) {
      float tv0 = tt[(size_t)(c0+cc  )*DIM + j];
      float tv1 = tt[(size_t)(c0+cc+1)*DIM + j];
      float tv2 = tt[(size_t)(c0+cc+2)*DIM + j];
      float tv3 = tt[(size_t)(c0+cc+3)*DIM + j];
      #pragma unroll
      for (int ri=0;ri<16;++ri) {
        float4 av = *(const float4*)&at[ri][cc];
        acc[ri] = fmaf(av.x, tv0, acc[ri]);
        acc[ri] = fmaf(av.y, tv1, acc[ri]);
        acc[ri] = fmaf(av.z, tv2, acc[ri]);
        acc[ri] = fmaf(av.w, tv3, acc[ri]);
      }
    }
  }
  float bj = bias[j];
  for (int ri=0;ri<16;++ri) {
    int r = r0+ri;
    if (r < NM)
      hout[(size_t)r*DIM + j] = fmaxf(acc[ri] + bj, 0.f) + hin[(size_t)r*DIM + j];
  }
}

// ---------------- output heads ----------------------------------------------------
__global__ __launch_bounds__(192) void k_heads(
    const float* __restrict__ h, const float* __restrict__ Wop, const float* __restrict__ bop,
    const float* __restrict__ Wrp, const float* __restrict__ brp,
    float* __restrict__ out, int N, int M) {
  int r = blockIdx.x, j = threadIdx.x;
  __shared__ float x[DIM];
  if (j < DIM) x[j] = h[(size_t)r*DIM + j];
  __syncthreads();
  if (r < N) {
    if (j < 151) {
      float a = bop[j];
      for (int k=0;k<DIM;++k) a = fmaf(x[k], Wop[k*151 + j], a);
      out[(size_t)r*151 + j] = a;
    }
  } else {
    int e = r - N;
    if (j < 51) {
      float a = brp[j];
      for (int k=0;k<DIM;++k) a = fmaf(x[k], Wrp[k*51 + j], a);
      out[(size_t)N*151 + (size_t)e*51 + j] = a;
    }
  }
}

extern "C" void kernel_launch(void* const* d_in, const int* in_sizes, int n_in,
                              void* d_out, int out_size, void* d_ws, size_t ws_size,
                              hipStream_t stream) {
  const float* roi   = (const float*)d_in[0];
  const float* logit = (const float*)d_in[1];
  const float* bbox  = (const float*)d_in[2];
  const float* uni   = (const float*)d_in[3];
  const int*   pairs = (const int*)d_in[4];
  const float* We1 = (const float*)d_in[5];
  const float* be1 = (const float*)d_in[6];
  const float* We2 = (const float*)d_in[7];
  const float* be2 = (const float*)d_in[8];
  const float* Wc  = (const float*)d_in[9];
  const float* bc  = (const float*)d_in[10];
  const float* Ws_ = (const float*)d_in[11];
  const float* bs  = (const float*)d_in[12];
  const float* Wob = (const float*)d_in[13];
  const float* bob = (const float*)d_in[14];
  const float* Wbgm= (const float*)d_in[15];
  const float* bbgm= (const float*)d_in[16];
  const float* Wq  = (const float*)d_in[17];
  const float* bq  = (const float*)d_in[18];
  const float* Wk  = (const float*)d_in[19];
  const float* bkk = (const float*)d_in[20];
  const float* Wv  = (const float*)d_in[21];
  const float* bv  = (const float*)d_in[22];
  const float* Wo  = (const float*)d_in[23];
  const float* bo  = (const float*)d_in[24];
  const float* Wr1 = (const float*)d_in[25];
  const float* br1 = (const float*)d_in[26];
  const float* Wr2 = (const float*)d_in[27];
  const float* br2 = (const float*)d_in[28];
  const float* gW  = (const float*)d_in[29];
  const float* gb  = (const float*)d_in[30];
  const float* Wop = (const float*)d_in[31];
  const float* bop = (const float*)d_in[32];
  const float* Wrp = (const float*)d_in[33];
  const float* brp = (const float*)d_in[34];
  float* out = (float*)d_out;

  const int M  = in_sizes[4] / 2;       // 2256
  const int N  = in_sizes[2] / 4;       // 48
  const int NM = N + M;                 // 2304

  // workspace carve-up (~95 MB total)
  char* p = (char*)d_ws;
  auto take = [&](size_t b) { void* r = (void*)p; p += (b + 255) & ~(size_t)255; return r; };
  __hip_bfloat16* Cs   = (__hip_bfloat16*)take((size_t)3*KTOT*DIM*sizeof(__hip_bfloat16));
  float* cbias         = (float*)take((size_t)3*HWSZ*DIM*sizeof(float));
  unsigned char* code  = (unsigned char*)take((size_t)M*HWSZ);
  float* out3          = (float*)take((size_t)M*3*DIM*sizeof(float));
  float* part          = (float*)take((size_t)8*M*3*DIM*sizeof(float));
  float* ha            = (float*)take((size_t)NM*DIM*sizeof(float));
  float* hb            = (float*)take((size_t)NM*DIM*sizeof(float));
  float* tb            = (float*)take((size_t)NM*DIM*sizeof(float));
  float* adj           = (float*)take((size_t)NM*NM*sizeof(float));
  (void)ws_size; (void)n_in; (void)out_size;

  k_objfeats<<<N, DIM, 0, stream>>>(roi, logit, bbox, We1, be1, We2, be2, ha);
  k_masks<<<(M+255)/256, 256, 0, stream>>>(bbox, pairs, M, code);
  k_build_cs<<<dim3(HWSZ, 8, 3), 128, 0, stream>>>(Wc, bc, Ws_, Wob, Wbgm, Cs, cbias);
  k_bigproj<<<dim3(3, (M+63)/64, 8), 256, 0, stream>>>(uni, Cs, code, part, M);
  k_reduce_out3<<<M, DIM, 0, stream>>>(part, code, cbias, bs, bob, bbgm, out3, M);
  k_attention<<<M, DIM, 0, stream>>>(out3, Wq, bq, Wk, bkk, Wv, bv, Wo, bo,
                                     Wr1, br1, Wr2, br2, ha, M, N);
  k_adj_init<<<(NM*NM+255)/256, 256, 0, stream>>>(adj, NM);
  k_adj_scatter<<<(M+255)/256, 256, 0, stream>>>(pairs, adj, M, N);
  k_adj_norm<<<NM, 256, 0, stream>>>(adj, NM);
  float* hc = ha; float* hn = hb;
  for (int l = 0; l < 4; ++l) {
    k_gcn_lin<<<NM, DIM, 0, stream>>>(hc, gW + (size_t)l*DIM*DIM, tb, NM);
    k_gcn_spmm<<<(NM+15)/16, DIM, 0, stream>>>(adj, tb, gb + (size_t)l*DIM, hc, hn, NM);
    float* tmp = hc; hc = hn; hn = tmp;
  }
  k_heads<<<NM, 192, 0, stream>>>(hc, Wop, bop, Wrp, brp, out, N, M);
}

// Round 2
// 1358.416 us; speedup vs baseline: 2.7474x; 2.7474x over previous
//
#include <hip/hip_runtime.h>
#include <hip/hip_bf16.h>
#include <string.h>

#define DIM  128
#define HWSZ 196
#define CCH  256
#define KTOT (CCH*HWSZ)    // 50176 (stage-1 K domain per pair)
#define K2   (HWSZ*DIM)    // 25088 (stage-2 K domain, hw*128+d)
#define KC2  14            // stage-2 split-K chunks (25088 = 14*1792, 1792 = 14 hw * 128)

typedef __attribute__((ext_vector_type(8))) short short8;
typedef __attribute__((ext_vector_type(4))) float f32x4;

union FragU { uint4 u; short8 h; };

static __device__ inline unsigned pk2bf(float lo, float hi) {
  union { __hip_bfloat16 h; unsigned short u; } a, b;
  a.h = __float2bfloat16(lo); b.h = __float2bfloat16(hi);
  return (unsigned)a.u | ((unsigned)b.u << 16);
}
static __device__ inline unsigned short bf1(float x) {
  union { __hip_bfloat16 h; unsigned short u; } a; a.h = __float2bfloat16(x); return a.u;
}

// ---------------- obj_feats: relu([roi|logit|bbox]@We1+be1)@We2+be2 -> h[0:48] ----
__global__ __launch_bounds__(128) void k_objfeats(
    const float* __restrict__ roi, const float* __restrict__ logit,
    const float* __restrict__ bbox,
    const float* __restrict__ We1, const float* __restrict__ be1,
    const float* __restrict__ We2, const float* __restrict__ be2,
    float* __restrict__ h) {
  const int i = blockIdx.x, j = threadIdx.x;
  __shared__ float t1[DIM];
  float acc = be1[j];
  const float* r = roi + (size_t)i*4096;
  for (int k = 0; k < 4096; ++k) acc = fmaf(r[k], We1[(size_t)k*DIM + j], acc);
  const float* lg = logit + (size_t)i*151;
  for (int k = 0; k < 151; ++k) acc = fmaf(lg[k], We1[(size_t)(4096+k)*DIM + j], acc);
  const float* bb = bbox + (size_t)i*4;
  for (int k = 0; k < 4; ++k) acc = fmaf(bb[k], We1[(size_t)(4247+k)*DIM + j], acc);
  t1[j] = fmaxf(acc, 0.f);
  __syncthreads();
  float a2 = be2[j];
  for (int k = 0; k < DIM; ++k) a2 = fmaf(t1[k], We2[k*DIM + j], a2);
  h[(size_t)i*DIM + j] = a2;
}

// ---------------- per-pair box masks -> 2-bit code (s | o<<1) per (m,hw) --------
__global__ void k_masks(const float* __restrict__ bbox, const int* __restrict__ pairs,
                        int M, unsigned char* __restrict__ code) {
  int m = blockIdx.x * blockDim.x + threadIdx.x;
  if (m >= M) return;
  int s = pairs[2*m], o = pairs[2*m+1];
  float sx1=bbox[4*s],   sy1=bbox[4*s+1], sx2=bbox[4*s+2], sy2=bbox[4*s+3];
  float ox1=bbox[4*o],   oy1=bbox[4*o+1], ox2=bbox[4*o+2], oy2=bbox[4*o+3];
  float ux = fminf(sx1, ox1), uy = fminf(sy1, oy1);
  float x0=sx1-ux, x1=sx2-ux, x2=ox1-ux, x3=ox2-ux;
  float y0=sy1-uy, y1=sy2-uy, y2=oy1-uy, y3=oy2-uy;
  float xf = 14.f / fmaxf(x1, x3);
  float yf = 14.f / fmaxf(y1, y3);
  int xp0=(int)rintf(x0*xf), xp1=(int)rintf(x1*xf), xp2=(int)rintf(x2*xf), xp3=(int)rintf(x3*xf);
  int yp0=(int)rintf(y0*yf), yp1=(int)rintf(y1*yf), yp2=(int)rintf(y2*yf), yp3=(int)rintf(y3*yf);
  unsigned char* cm = code + (size_t)m*HWSZ;
  for (int hh = 0; hh < 14; ++hh)
    for (int ww = 0; ww < 14; ++ww) {
      int sm = (hh>=xp0 && hh<xp1 && ww>=yp0 && ww<yp1) ? 1 : 0;
      int om = (hh>=xp2 && hh<xp3 && ww>=yp2 && ww<yp3) ? 1 : 0;
      cm[hh*14+ww] = (unsigned char)(sm | (om<<1));
    }
}

// ---------------- builder: Wc f32 [d][256] -> Wcb bf16 [d][264] (16B pad/row) -----
__global__ __launch_bounds__(256) void k_wcb(const float* __restrict__ Wc,
                                             unsigned short* __restrict__ Wcb) {
  int d = blockIdx.x;
  for (int c = threadIdx.x; c < 264; c += 256)
    Wcb[d*264 + c] = (c < 256) ? bf1(Wc[d*256 + c]) : (unsigned short)0;
}

// ---------------- builder: W_t [(d*196+hw)][j] f32 -> BT[t][j][hw*128+d] bf16 -----
__global__ __launch_bounds__(256) void k_btrans(
    const float* __restrict__ Ws, const float* __restrict__ Wob,
    const float* __restrict__ Wbgm, unsigned short* __restrict__ BT) {
  const int hw = blockIdx.x, dblk = blockIdx.y, t = blockIdx.z;
  const int d0 = dblk * 64;
  const float* __restrict__ W = (t==0) ? Ws : (t==1) ? Wob : Wbgm;
  __shared__ unsigned short sT[64][130];   // [d][j], padded vs bank conflicts
  for (int idx = threadIdx.x; idx < 64*128; idx += 256) {
    int dd = idx >> 7, j = idx & 127;
    sT[dd][j] = bf1(W[((size_t)(d0+dd)*HWSZ + hw)*DIM + j]);
  }
  __syncthreads();
  unsigned* outw = (unsigned*)BT;
  for (int idx = threadIdx.x; idx < 128*32; idx += 256) {
    int j = idx >> 5, pr = idx & 31, d = pr*2;
    unsigned v = (unsigned)sT[d][j] | ((unsigned)sT[d+1][j] << 16);
    size_t el = ((size_t)(t*128 + j))*K2 + hw*128 + d0 + d;  // even
    outw[el >> 1] = v;
  }
}

// ---------------- stage 1: ufT[m][hw][d] = uT@WcT + bc   (bf16 MFMA) -------------
__global__ __launch_bounds__(256, 2) void k_uf(
    const float* __restrict__ uni, const unsigned short* __restrict__ Wcb,
    const float* __restrict__ bc, unsigned short* __restrict__ ufT, int M) {
  const int m = blockIdx.x;
  const int tid = threadIdx.x;
  const int wave = tid >> 6, lane = tid & 63, quad = lane >> 4, l15 = lane & 15;
  __shared__ __attribute__((aligned(16))) char pool[50176];
  // loop layout: At (208 rows x 80B) at 0 ; Wck (128 rows x 80B) at 16640
  char* At  = pool;
  char* Wck = pool + 16640;
  const float* u = uni + (size_t)m * KTOT;

  // zero hw-pad rows 196..207 of At (stay zero across k-steps)
  if (tid < 240) ((int*)(At + 196*80))[tid] = 0;

  f32x4 acc[13][2];
  #pragma unroll
  for (int a = 0; a < 13; ++a) { acc[a][0] = (f32x4)0.f; acc[a][1] = (f32x4)0.f; }

  const float bcv0 = bc[wave*32 + l15];
  const float bcv1 = bc[wave*32 + 16 + l15];

  for (int cc = 0; cc < 8; ++cc) {
    const int c0 = cc * 32;
    __syncthreads();
    // stage A^T: u[c][hw] f32 -> At[hw][c_local] bf16 (transpose, c-pair packed b32)
    for (int idx = tid; idx < 784; idx += 256) {
      int cp = idx / 49, h4 = (idx - cp*49) * 4;
      const float4 a4 = *(const float4*)&u[(size_t)(c0 + 2*cp)*HWSZ + h4];
      const float4 b4 = *(const float4*)&u[(size_t)(c0 + 2*cp + 1)*HWSZ + h4];
      unsigned w0 = pk2bf(a4.x, b4.x), w1 = pk2bf(a4.y, b4.y);
      unsigned w2 = pk2bf(a4.z, b4.z), w3 = pk2bf(a4.w, b4.w);
      *(unsigned*)(At + (h4  )*80 + cp*4) = w0;
      *(unsigned*)(At + (h4+1)*80 + cp*4) = w1;
      *(unsigned*)(At + (h4+2)*80 + cp*4) = w2;
      *(unsigned*)(At + (h4+3)*80 + cp*4) = w3;
    }
    // stage Wck[d][c_local] bf16 from Wcb [d][264]
    for (int idx = tid; idx < 512; idx += 256) {
      int d = idx >> 2, part = idx & 3;
      uint4 v = *(const uint4*)((const char*)Wcb + (size_t)d*528 + c0*2 + part*16);
      *(uint4*)(Wck + d*80 + part*16) = v;
    }
    __syncthreads();
    // MFMA: wave handles d-tiles {2w, 2w+1} x 13 hw-tiles
    FragU b0, b1;
    b0.u = *(const uint4*)(Wck + (wave*32      + l15)*80 + quad*16);
    b1.u = *(const uint4*)(Wck + (wave*32 + 16 + l15)*80 + quad*16);
    #pragma unroll
    for (int hf = 0; hf < 13; ++hf) {
      FragU a;
      a.u = *(const uint4*)(At + (hf*16 + l15)*80 + quad*16);
      acc[hf][0] = __builtin_amdgcn_mfma_f32_16x16x32_bf16(a.h, b0.h, acc[hf][0], 0, 0, 0);
      acc[hf][1] = __builtin_amdgcn_mfma_f32_16x16x32_bf16(a.h, b1.h, acc[hf][1], 0, 0, 0);
    }
  }
  // epilogue: acc -> LDS Cout[hw][d] bf16 (+bc), then coalesced store
  __syncthreads();
  unsigned short* Cout = (unsigned short*)pool;  // 196 x 128 bf16 (50176 B)
  #pragma unroll
  for (int hf = 0; hf < 13; ++hf) {
    #pragma unroll
    for (int b = 0; b < 2; ++b) {
      int d = wave*32 + b*16 + l15;
      float bias = b ? bcv1 : bcv0;
      #pragma unroll
      for (int r = 0; r < 4; ++r) {
        int hw = hf*16 + quad*4 + r;
        if (hw < HWSZ) Cout[hw*128 + d] = bf1(acc[hf][b][r] + bias);
      }
    }
  }
  __syncthreads();
  char* dst = (char*)ufT + (size_t)m * (K2*2);
  for (int idx = tid; idx < 3136; idx += 256) {
    int r = idx >> 4, part = idx & 15;
    uint4 v = *(const uint4*)(pool + r*256 + part*16);
    *(uint4*)(dst + r*256 + part*16) = v;
  }
}

// ---------------- stage 2: masked projection, bf16 MFMA, split-K -----------------
// part[kc][m][t][j] = sum over K-chunk of (ufT[m][k]&mask_t) * BT_t[j][k]
__global__ __launch_bounds__(256, 2) void k_proj(
    const unsigned short* __restrict__ ufT, const unsigned short* __restrict__ BT,
    const unsigned char* __restrict__ code, float* __restrict__ part, int M) {
  const int kc = blockIdx.x;          // 0..13
  const int mt = blockIdx.y;          // 0..35
  const int m0 = mt * 64;
  const int tid = threadIdx.x;
  const int wave = tid >> 6, lane = tid & 63, quad = lane >> 4, l15 = lane & 15;
  const int hw0 = kc * 14;
  const int kbase0 = kc * 1792;

  __shared__ __attribute__((aligned(16))) char As[64*80];       // [m][32k] bf16 +16B pad
  __shared__ __attribute__((aligned(16))) char Bs[3*128*80];    // [t][j][32k] bf16 +pad
  __shared__ unsigned char codeL[64][14];

  for (int idx = tid; idx < 64*14; idx += 256) {
    int ml = idx / 14, hwl = idx - ml*14;
    int gm = m0 + ml;
    codeL[ml][hwl] = (gm < M) ? code[(size_t)gm*HWSZ + hw0 + hwl] : (unsigned char)0;
  }

  f32x4 acc[4][6];
  #pragma unroll
  for (int a = 0; a < 4; ++a)
    #pragma unroll
    for (int q = 0; q < 6; ++q) acc[a][q] = (f32x4)0.f;

  for (int step = 0; step < 56; ++step) {
    const int kbase = kbase0 + step*32;
    __syncthreads();
    { // stage A: 64 m-rows x 32k
      int ml = tid >> 2, pt = tid & 3;
      int gm = m0 + ml;
      uint4 v = make_uint4(0,0,0,0);
      if (gm < M)
        v = *(const uint4*)((const char*)ufT + (size_t)gm*(K2*2) + (size_t)kbase*2 + pt*16);
      *(uint4*)(As + ml*80 + pt*16) = v;
    }
    { // stage B: 3t x 128j x 32k from BT[t][j][K]
      for (int idx = tid; idx < 1536; idx += 256) {
        int t = idx >> 9, rem = idx & 511, j = rem >> 2, pt = idx & 3;
        uint4 v = *(const uint4*)((const char*)BT +
                    ((size_t)(t*128 + j)*K2 + kbase)*2 + pt*16);
        *(uint4*)(Bs + (t*128 + j)*80 + pt*16) = v;
      }
    }
    __syncthreads();
    const int hwl = step >> 2;
    FragU araw[4]; unsigned char cd[4];
    #pragma unroll
    for (int mf = 0; mf < 4; ++mf) {
      araw[mf].u = *(const uint4*)(As + (mf*16 + l15)*80 + quad*16);
      cd[mf] = codeL[mf*16 + l15][hwl];
    }
    int tcur = -1;
    FragU am[4];
    #pragma unroll
    for (int q = 0; q < 6; ++q) {
      const int combo = wave*6 + q;
      const int t = combo >> 3, jt = combo & 7;
      if (t != tcur) {
        tcur = t;
        #pragma unroll
        for (int mf = 0; mf < 4; ++mf) {
          int c = cd[mf];
          int bit = (t == 0) ? (c & 1) : (t == 1) ? ((c >> 1) & 1) : (c == 0 ? 1 : 0);
          unsigned mk = bit ? 0xFFFFFFFFu : 0u;
          am[mf].u.x = araw[mf].u.x & mk; am[mf].u.y = araw[mf].u.y & mk;
          am[mf].u.z = araw[mf].u.z & mk; am[mf].u.w = araw[mf].u.w & mk;
        }
      }
      FragU b;
      b.u = *(const uint4*)(Bs + (t*128 + jt*16 + l15)*80 + quad*16);
      #pragma unroll
      for (int mf = 0; mf < 4; ++mf)
        acc[mf][q] = __builtin_amdgcn_mfma_f32_16x16x32_bf16(am[mf].h, b.h, acc[mf][q], 0, 0, 0);
    }
  }
  // epilogue -> part[kc][m][t][j]
  #pragma unroll
  for (int q = 0; q < 6; ++q) {
    const int combo = wave*6 + q;
    const int t = combo >> 3, jt = combo & 7;
    const int j = jt*16 + l15;
    #pragma unroll
    for (int mf = 0; mf < 4; ++mf) {
      #pragma unroll
      for (int r = 0; r < 4; ++r) {
        int gm = m0 + mf*16 + quad*4 + r;
        if (gm < M)
          part[(((size_t)kc*M + gm)*3 + t)*DIM + j] = acc[mf][q][r];
      }
    }
  }
}

// ---------------- reduce split-K partials + bias -> xseq out3 (M,3,128) ----------
__global__ __launch_bounds__(128) void k_reduce(
    const float* __restrict__ part,
    const float* __restrict__ bs, const float* __restrict__ bob,
    const float* __restrict__ bbgm, float* __restrict__ out3, int M) {
  const int m = blockIdx.x, j = threadIdx.x;
  const float bias[3] = {bs[j], bob[j], bbgm[j]};
  for (int t = 0; t < 3; ++t) {
    float s = bias[t];
    for (int kc = 0; kc < KC2; ++kc)
      s += part[(((size_t)kc*M + m)*3 + t)*DIM + j];
    out3[((size_t)m*3 + t)*DIM + j] = s;
  }
}

// ---------------- batched attention + rel MLP: 8 pairs per block -----------------
__global__ __launch_bounds__(256) void k_attn(
    const float* __restrict__ xseq,
    const float* __restrict__ Wq, const float* __restrict__ bq,
    const float* __restrict__ Wk, const float* __restrict__ bk_,
    const float* __restrict__ Wv, const float* __restrict__ bv,
    const float* __restrict__ Wo, const float* __restrict__ bo,
    const float* __restrict__ Wr1, const float* __restrict__ br1,
    const float* __restrict__ Wr2, const float* __restrict__ br2,
    float* __restrict__ h, int M, int N) {
  __shared__ float pool[16960];
  float* sX = pool;            // 8*3*128      (later reused as O)
  float* sW = pool + 3072;     // 32*128 staging
  float* sQ = pool + 7168;
  float* sK = pool + 10240;    // later reused as C (8*384)
  float* sV = pool + 13312;    // later reused as R (8*128)
  float* sP = pool + 16384;    // 8*8*9

  const int tid = threadIdx.x;
  const int p = tid >> 5, lane32 = tid & 31, j4 = lane32 * 4;
  const int gm = blockIdx.x * 8 + p;
  const bool valid = (gm < M);

  // load X
  {
    const float* src = xseq + (size_t)blockIdx.x * 8 * 384;
    for (int idx = tid; idx < 768; idx += 256) {   // 768 float4 = 3072 f
      int mm = idx / 96;
      float4 v = make_float4(0,0,0,0);
      if (blockIdx.x*8 + mm < M) v = ((const float4*)src)[idx];
      ((float4*)sX)[idx] = v;
    }
  }
  __syncthreads();

  // QKV projections
  const float* Wm[3] = {Wq, Wk, Wv};
  const float* bm[3] = {bq, bk_, bv};
  float* Om[3];
  Om[0] = sQ; Om[1] = sK; Om[2] = sV;
  for (int mat = 0; mat < 3; ++mat) {
    float a0[3] = {0.f,0.f,0.f}, a1[3] = {0.f,0.f,0.f}, a2[3] = {0.f,0.f,0.f}, a3[3] = {0.f,0.f,0.f};
    for (int kc = 0; kc < 4; ++kc) {
      __syncthreads();
      for (int idx = tid; idx < 1024; idx += 256) {
        int kk = idx >> 5, jq = idx & 31;
        ((float4*)sW)[kk*32 + jq] = *(const float4*)&Wm[mat][(size_t)(kc*32+kk)*DIM + jq*4];
      }
      __syncthreads();
      for (int kk = 0; kk < 32; ++kk) {
        float4 w = ((float4*)sW)[kk*32 + lane32];
        #pragma unroll
        for (int t = 0; t < 3; ++t) {
          float x = sX[(p*3 + t)*128 + kc*32 + kk];
          a0[t] = fmaf(x, w.x, a0[t]); a1[t] = fmaf(x, w.y, a1[t]);
          a2[t] = fmaf(x, w.z, a2[t]); a3[t] = fmaf(x, w.w, a3[t]);
        }
      }
    }
    float4 bb = *(const float4*)&bm[mat][j4];
    __syncthreads();
    #pragma unroll
    for (int t = 0; t < 3; ++t) {
      Om[mat][(p*3 + t)*128 + j4    ] = a0[t] + bb.x;
      Om[mat][(p*3 + t)*128 + j4 + 1] = a1[t] + bb.y;
      Om[mat][(p*3 + t)*128 + j4 + 2] = a2[t] + bb.z;
      Om[mat][(p*3 + t)*128 + j4 + 3] = a3[t] + bb.w;
    }
  }
  __syncthreads();
  // scores
  for (int idx = tid; idx < 576; idx += 256) {
    int pp = idx / 72, rem = idx % 72, hh = rem / 9, r2 = rem % 9, qt = r2 / 3, kt = r2 % 3;
    float s = 0.f;
    for (int d = 0; d < 16; ++d)
      s = fmaf(sQ[(pp*3 + qt)*128 + hh*16 + d], sK[(pp*3 + kt)*128 + hh*16 + d], s);
    sP[(pp*8 + hh)*9 + qt*3 + kt] = s * 0.25f;
  }
  __syncthreads();
  if (tid < 192) {
    int pp = tid / 24, rem = tid % 24, hh = rem / 3, qt = rem % 3;
    float* pr = &sP[(pp*8 + hh)*9 + qt*3];
    float mx = fmaxf(pr[0], fmaxf(pr[1], pr[2]));
    float e0 = expf(pr[0]-mx), e1 = expf(pr[1]-mx), e2 = expf(pr[2]-mx);
    float inv = 1.f/(e0+e1+e2);
    pr[0] = e0*inv; pr[1] = e1*inv; pr[2] = e2*inv;
  }
  __syncthreads();
  // PV -> sX (reused as O)
  {
    int hh = j4 >> 4;
    float o[3][4];
    #pragma unroll
    for (int qt = 0; qt < 3; ++qt)
      #pragma unroll
      for (int q = 0; q < 4; ++q) o[qt][q] = 0.f;
    #pragma unroll
    for (int kt = 0; kt < 3; ++kt) {
      float4 v = *(const float4*)&sV[(p*3 + kt)*128 + j4];
      #pragma unroll
      for (int qt = 0; qt < 3; ++qt) {
        float w = sP[(p*8 + hh)*9 + qt*3 + kt];
        o[qt][0] = fmaf(w, v.x, o[qt][0]); o[qt][1] = fmaf(w, v.y, o[qt][1]);
        o[qt][2] = fmaf(w, v.z, o[qt][2]); o[qt][3] = fmaf(w, v.w, o[qt][3]);
      }
    }
    __syncthreads();
    #pragma unroll
    for (int qt = 0; qt < 3; ++qt)
      *(float4*)&sX[(p*3 + qt)*128 + j4] = make_float4(o[qt][0],o[qt][1],o[qt][2],o[qt][3]);
  }
  __syncthreads();
  // Wo projection -> sK reused as C[p][384]
  {
    float a0[3] = {0,0,0}, a1[3] = {0,0,0}, a2[3] = {0,0,0}, a3[3] = {0,0,0};
    for (int kc = 0; kc < 4; ++kc) {
      __syncthreads();
      for (int idx = tid; idx < 1024; idx += 256) {
        int kk = idx >> 5, jq = idx & 31;
        ((float4*)sW)[kk*32 + jq] = *(const float4*)&Wo[(size_t)(kc*32+kk)*DIM + jq*4];
      }
      __syncthreads();
      for (int kk = 0; kk < 32; ++kk) {
        float4 w = ((float4*)sW)[kk*32 + lane32];
        #pragma unroll
        for (int t = 0; t < 3; ++t) {
          float x = sX[(p*3 + t)*128 + kc*32 + kk];
          a0[t] = fmaf(x, w.x, a0[t]); a1[t] = fmaf(x, w.y, a1[t]);
          a2[t] = fmaf(x, w.z, a2[t]); a3[t] = fmaf(x, w.w, a3[t]);
        }
      }
    }
    float4 bb = *(const float4*)&bo[j4];
    __syncthreads();
    #pragma unroll
    for (int t = 0; t < 3; ++t) {
      sK[p*384 + t*128 + j4    ] = a0[t] + bb.x;
      sK[p*384 + t*128 + j4 + 1] = a1[t] + bb.y;
      sK[p*384 + t*128 + j4 + 2] = a2[t] + bb.z;
      sK[p*384 + t*128 + j4 + 3] = a3[t] + bb.w;
    }
  }
  __syncthreads();
  // rel layer 1: C[384] @ Wr1 -> relu -> sV reused as R[p][128]
  {
    float a0=0,a1=0,a2=0,a3=0;
    for (int kc = 0; kc < 12; ++kc) {
      __syncthreads();
      for (int idx = tid; idx < 1024; idx += 256) {
        int kk = idx >> 5, jq = idx & 31;
        ((float4*)sW)[kk*32 + jq] = *(const float4*)&Wr1[(size_t)(kc*32+kk)*DIM + jq*4];
      }
      __syncthreads();
      for (int kk = 0; kk < 32; ++kk) {
        float4 w = ((float4*)sW)[kk*32 + lane32];
        float x = sK[p*384 + kc*32 + kk];
        a0 = fmaf(x, w.x, a0); a1 = fmaf(x, w.y, a1);
        a2 = fmaf(x, w.z, a2); a3 = fmaf(x, w.w, a3);
      }
    }
    float4 bb = *(const float4*)&br1[j4];
    __syncthreads();
    sV[p*128 + j4    ] = fmaxf(a0 + bb.x, 0.f);
    sV[p*128 + j4 + 1] = fmaxf(a1 + bb.y, 0.f);
    sV[p*128 + j4 + 2] = fmaxf(a2 + bb.z, 0.f);
    sV[p*128 + j4 + 3] = fmaxf(a3 + bb.w, 0.f);
  }
  __syncthreads();
  // rel layer 2 -> h[N+m]
  {
    float a0=0,a1=0,a2=0,a3=0;
    for (int kc = 0; kc < 4; ++kc) {
      __syncthreads();
      for (int idx = tid; idx < 1024; idx += 256) {
        int kk = idx >> 5, jq = idx & 31;
        ((float4*)sW)[kk*32 + jq] = *(const float4*)&Wr2[(size_t)(kc*32+kk)*DIM + jq*4];
      }
      __syncthreads();
      for (int kk = 0; kk < 32; ++kk) {
        float4 w = ((float4*)sW)[kk*32 + lane32];
        float x = sV[p*128 + kc*32 + kk];
        a0 = fmaf(x, w.x, a0); a1 = fmaf(x, w.y, a1);
        a2 = fmaf(x, w.z, a2); a3 = fmaf(x, w.w, a3);
      }
    }
    if (valid) {
      float4 bb = *(const float4*)&br2[j4];
      *(float4*)&h[(size_t)(N + gm)*DIM + j4] =
        make_float4(a0+bb.x, a1+bb.y, a2+bb.z, a3+bb.w);
    }
  }
}

// ---------------- sparse GCN adjacency build -------------------------------------
__global__ void k_zero(int* __restrict__ a, int n) {
  int i = blockIdx.x*256 + threadIdx.x;
  if (i < n) a[i] = 0;
}

__global__ void k_edge_build(const int* __restrict__ pairs, int M, int N,
                             int* __restrict__ nodeCnt, int* __restrict__ nodeCol,
                             int* __restrict__ keyCnt, int* __restrict__ slot) {
  int e = blockIdx.x*256 + threadIdx.x;
  if (e >= M) return;
  int s = pairs[2*e], o = pairs[2*e+1];
  int key = min(s,o)*N + max(s,o);
  int pos = atomicAdd(&keyCnt[key], 1);
  if (pos < 2) slot[key*2 + pos] = e;
  int i1 = atomicAdd(&nodeCnt[s], 2);
  nodeCol[s*160 + i1] = o;          // n2n
  nodeCol[s*160 + i1 + 1] = N + e;  // n2e
  int i2 = atomicAdd(&nodeCnt[o], 1);
  nodeCol[o*160 + i2] = N + e;      // n2e
}

__global__ void k_edge_partner(const int* __restrict__ pairs, int M, int N,
                               const int* __restrict__ keyCnt, const int* __restrict__ slot,
                               int* __restrict__ partner, float* __restrict__ einv) {
  int e = blockIdx.x*256 + threadIdx.x;
  if (e >= M) return;
  int s = pairs[2*e], o = pairs[2*e+1];
  int key = min(s,o)*N + max(s,o);
  int cnt = keyCnt[key];
  partner[e] = (cnt == 2) ? (slot[key*2] + slot[key*2+1] - e) : -1;
  einv[e] = 1.f / (float)(2 + cnt);
}

// ---------------- GCN: t = h@W (dense small), sparse normalized aggregate --------
__global__ __launch_bounds__(128) void k_gcn_lin(
    const float* __restrict__ h, const float* __restrict__ W,
    float* __restrict__ t, int NM) {
  int r = blockIdx.x, j = threadIdx.x;
  __shared__ float x[DIM];
  x[j] = h[(size_t)r*DIM + j];
  __syncthreads();
  float a = 0.f;
  for (int k = 0; k < DIM; k += 4) {
    float4 xv = *(const float4*)&x[k];
    a = fmaf(xv.x, W[(k  )*DIM+j], a);
    a = fmaf(xv.y, W[(k+1)*DIM+j], a);
    a = fmaf(xv.z, W[(k+2)*DIM+j], a);
    a = fmaf(xv.w, W[(k+3)*DIM+j], a);
  }
  t[(size_t)r*DIM + j] = a;
}

__global__ __launch_bounds__(128) void k_gcn_spmm(
    const float* __restrict__ tt, const float* __restrict__ bias,
    const float* __restrict__ hin, float* __restrict__ hout,
    const int* __restrict__ nodeCnt, const int* __restrict__ nodeCol,
    const int* __restrict__ pairs, const int* __restrict__ partner,
    const float* __restrict__ einv, int N, int M) {
  int r = blockIdx.x, j = threadIdx.x;
  float acc = tt[(size_t)r*DIM + j];   // self (eye)
  float inv;
  if (r < N) {
    int cnt = nodeCnt[r];
    for (int it = 0; it < cnt; ++it)
      acc += tt[(size_t)nodeCol[r*160 + it]*DIM + j];
    inv = 1.f / (float)(1 + cnt);
  } else {
    int e = r - N;
    int s = pairs[2*e], o = pairs[2*e+1];
    acc += tt[(size_t)s*DIM + j] + tt[(size_t)o*DIM + j];
    int pt = partner[e];
    if (pt >= 0) acc += tt[(size_t)(N + pt)*DIM + j];
    inv = einv[e];
  }
  hout[(size_t)r*DIM + j] = fmaxf(acc*inv + bias[j], 0.f) + hin[(size_t)r*DIM + j];
}

// ---------------- output heads ----------------------------------------------------
__global__ __launch_bounds__(192) void k_heads(
    const float* __restrict__ h, const float* __restrict__ Wop, const float* __restrict__ bop,
    const float* __restrict__ Wrp, const float* __restrict__ brp,
    float* __restrict__ out, int N, int M) {
  int r = blockIdx.x, j = threadIdx.x;
  __shared__ float x[DIM];
  if (j < DIM) x[j] = h[(size_t)r*DIM + j];
  __syncthreads();
  if (r < N) {
    if (j < 151) {
      float a = bop[j];
      for (int k=0;k<DIM;++k) a = fmaf(x[k], Wop[k*151 + j], a);
      out[(size_t)r*151 + j] = a;
    }
  } else {
    int e = r - N;
    if (j < 51) {
      float a = brp[j];
      for (int k=0;k<DIM;++k) a = fmaf(x[k], Wrp[k*51 + j], a);
      out[(size_t)N*151 + (size_t)e*51 + j] = a;
    }
  }
}

extern "C" void kernel_launch(void* const* d_in, const int* in_sizes, int n_in,
                              void* d_out, int out_size, void* d_ws, size_t ws_size,
                              hipStream_t stream) {
  const float* roi   = (const float*)d_in[0];
  const float* logit = (const float*)d_in[1];
  const float* bbox  = (const float*)d_in[2];
  const float* uni   = (const float*)d_in[3];
  const int*   pairs = (const int*)d_in[4];
  const float* We1 = (const float*)d_in[5];
  const float* be1 = (const float*)d_in[6];
  const float* We2 = (const float*)d_in[7];
  const float* be2 = (const float*)d_in[8];
  const float* Wc  = (const float*)d_in[9];
  const float* bc  = (const float*)d_in[10];
  const float* Ws_ = (const float*)d_in[11];
  const float* bs  = (const float*)d_in[12];
  const float* Wob = (const float*)d_in[13];
  const float* bob = (const float*)d_in[14];
  const float* Wbgm= (const float*)d_in[15];
  const float* bbgm= (const float*)d_in[16];
  const float* Wq  = (const float*)d_in[17];
  const float* bq  = (const float*)d_in[18];
  const float* Wk  = (const float*)d_in[19];
  const float* bkk = (const float*)d_in[20];
  const float* Wv  = (const float*)d_in[21];
  const float* bv  = (const float*)d_in[22];
  const float* Wo  = (const float*)d_in[23];
  const float* bo  = (const float*)d_in[24];
  const float* Wr1 = (const float*)d_in[25];
  const float* br1 = (const float*)d_in[26];
  const float* Wr2 = (const float*)d_in[27];
  const float* br2 = (const float*)d_in[28];
  const float* gW  = (const float*)d_in[29];
  const float* gb  = (const float*)d_in[30];
  const float* Wop = (const float*)d_in[31];
  const float* bop = (const float*)d_in[32];
  const float* Wrp = (const float*)d_in[33];
  const float* brp = (const float*)d_in[34];
  float* out = (float*)d_out;

  const int M  = in_sizes[4] / 2;   // 2256
  const int N  = in_sizes[2] / 4;   // 48
  const int NM = N + M;             // 2304

  char* p = (char*)d_ws;
  auto take = [&](size_t b) { void* r = (void*)p; p += (b + 255) & ~(size_t)255; return r; };
  unsigned short* Wcb = (unsigned short*)take((size_t)128*264*2);
  unsigned short* BT  = (unsigned short*)take((size_t)3*128*K2*2);
  unsigned short* ufT = (unsigned short*)take((size_t)M*K2*2);
  unsigned char* code = (unsigned char*)take((size_t)M*HWSZ);
  float* part         = (float*)take((size_t)KC2*M*3*DIM*sizeof(float));
  float* out3         = (float*)take((size_t)M*3*DIM*sizeof(float));
  float* ha           = (float*)take((size_t)NM*DIM*sizeof(float));
  float* hb           = (float*)take((size_t)NM*DIM*sizeof(float));
  float* tb           = (float*)take((size_t)NM*DIM*sizeof(float));
  int* nodeCnt        = (int*)take((size_t)N*sizeof(int));
  int* nodeCol        = (int*)take((size_t)N*160*sizeof(int));
  int* keyCnt         = (int*)take((size_t)N*N*sizeof(int));
  int* slot           = (int*)take((size_t)N*N*2*sizeof(int));
  int* partner        = (int*)take((size_t)M*sizeof(int));
  float* einv         = (float*)take((size_t)M*sizeof(float));
  (void)ws_size; (void)n_in; (void)out_size;

  // builders + masks + obj path
  k_wcb   <<<128, 256, 0, stream>>>(Wc, Wcb);
  k_btrans<<<dim3(HWSZ, 2, 3), 256, 0, stream>>>(Ws_, Wob, Wbgm, BT);
  k_masks <<<(M+255)/256, 256, 0, stream>>>(bbox, pairs, M, code);
  k_objfeats<<<N, DIM, 0, stream>>>(roi, logit, bbox, We1, be1, We2, be2, ha);

  // big path: stage1 + stage2 + reduce
  k_uf    <<<M, 256, 0, stream>>>(uni, Wcb, bc, ufT, M);
  k_proj  <<<dim3(KC2, (M+63)/64), 256, 0, stream>>>(ufT, BT, code, part, M);
  k_reduce<<<M, DIM, 0, stream>>>(part, bs, bob, bbgm, out3, M);

  // attention + rel
  k_attn<<<(M+7)/8, 256, 0, stream>>>(out3, Wq, bq, Wk, bkk, Wv, bv, Wo, bo,
                                      Wr1, br1, Wr2, br2, ha, M, N);

  // sparse adjacency build
  k_zero<<<(N + N*N + 255)/256, 256, 0, stream>>>(nodeCnt, N);       // nodeCnt
  k_zero<<<(N*N + 255)/256, 256, 0, stream>>>(keyCnt, N*N);          // keyCnt
  k_edge_build  <<<(M+255)/256, 256, 0, stream>>>(pairs, M, N, nodeCnt, nodeCol, keyCnt, slot);
  k_edge_partner<<<(M+255)/256, 256, 0, stream>>>(pairs, M, N, keyCnt, slot, partner, einv);

  // GCN x4
  float* hc = ha; float* hn = hb;
  for (int l = 0; l < 4; ++l) {
    k_gcn_lin <<<NM, DIM, 0, stream>>>(hc, gW + (size_t)l*DIM*DIM, tb, NM);
    k_gcn_spmm<<<NM, DIM, 0, stream>>>(tb, gb + (size_t)l*DIM, hc, hn,
                                       nodeCnt, nodeCol, pairs, partner, einv, N, M);
    float* tmp = hc; hc = hn; hn = tmp;
  }
  k_heads<<<NM, 192, 0, stream>>>(hc, Wop, bop, Wrp, brp, out, N, M);
}